// Round 12
// baseline (361.588 us; speedup 1.0000x reference)
//
#include <hip/hip_runtime.h>
#include <math.h>

typedef unsigned short u16;
typedef unsigned int u32;
typedef __attribute__((ext_vector_type(8))) short bf16x8;
typedef __attribute__((ext_vector_type(4))) float f32x4;

#define IMG 128
#define HWN 16384
#define NTOT 65536          // 4 * 16384 pixels
#define DIMC 384
#define CDIM 1152
#define NBATCH 4
#define NHEAD 8
#define CHD 48
#define KC 16
#define VSTR 152            // in3 row stride (elems): 19 x 16B units (odd) -> no quad imbalance

__device__ __forceinline__ u16 f2bf(float f) {
  union { float f; u32 u; } x; x.f = f;
  u32 r = x.u + 0x7fffu + ((x.u >> 16) & 1u);
  return (u16)(r >> 16);
}
__device__ __forceinline__ float bf2f(u16 v) {
  union { u32 u; float f; } x; x.u = ((u32)v) << 16;
  return x.f;
}
__device__ __forceinline__ void gload_lds16(const u16* g, u16* lds) {
  __builtin_amdgcn_global_load_lds((const __attribute__((address_space(1))) void*)g,
                                   (__attribute__((address_space(3))) void*)lds, 16, 0, 0);
}

// ---------------- tiny: convert w_qkv to bf16 ----------------
__global__ void convert_wq_kernel(const float* __restrict__ in, u16* __restrict__ out, int n) {
  int i = blockIdx.x * 256 + threadIdx.x;
  if (i < n) out[i] = f2bf(in[i]);
}

// ---------------- K0: x [b,c,n] f32 -> xT [b*n, c] bf16 ----------------
__global__ __launch_bounds__(256) void transpose_x_kernel(const float* __restrict__ x,
                                                          u16* __restrict__ xT) {
  __shared__ float tile[32][33];
  int n0 = blockIdx.x * 32, c0 = blockIdx.y * 32, b = blockIdx.z;
  const float* xb = x + (size_t)b * DIMC * HWN;
  u16* xTb = xT + (size_t)b * HWN * DIMC;
  int tx = threadIdx.x & 31, ty = threadIdx.x >> 5;
#pragma unroll
  for (int i = 0; i < 32; i += 8)
    tile[ty + i][tx] = xb[(size_t)(c0 + ty + i) * HWN + n0 + tx];
  __syncthreads();
  int cp = threadIdx.x & 15, nl = threadIdx.x >> 4;   // 16 c-pairs, 16 n-rows
#pragma unroll
  for (int i = 0; i < 2; i++) {
    int n = nl + i * 16;
    u32 o = (u32)f2bf(tile[cp * 2][n]) | ((u32)f2bf(tile[cp * 2 + 1][n]) << 16);
    *(u32*)&xTb[(size_t)(n0 + n) * DIMC + c0 + cp * 2] = o;
  }
}

// ---------------- GEMM (m97 structure + T2 swizzle): C = A[M,:K] * B[N,:K]^T ------
// Linear LDS dest (global_load_lds requirement); SOURCE octet pre-swizzled with
// (l&7)^(l>>3); fragment read XORs octet with row&7.  LDS(R,o) = global(R, o^(R&7)).
// 1-D grid.x = 8 * MBLK * (NBLK/8); XCD-aware decode (same n-tile -> same XCD).
template <int BF16OUT>
__global__ __launch_bounds__(256) void gemm_bt_kernel(
    const u16* __restrict__ A, const u16* __restrict__ B, void* __restrict__ Cout,
    int MBLK, int K, int lda, int ldb, int ldc,
    unsigned long long aStride, unsigned long long bStride, unsigned long long cStride) {
  __shared__ u16 As[128 * 64];
  __shared__ u16 Bs[128 * 64];
  int bz = blockIdx.z;
  const u16* Ab = A + (size_t)bz * aStride;
  const u16* Bb = B + (size_t)bz * bStride;
  int bid = blockIdx.x;
  int xcd = bid & 7, j = bid >> 3;
  int mb = j % MBLK, nb = (j / MBLK) * 8 + xcd;
  int n0 = nb * 128, m0 = mb * 128;
  int t = threadIdx.x;
  int wave = t >> 6, lane = t & 63;
  int wm = (wave >> 1) * 64, wn = (wave & 1) * 64;
  int lr = lane & 15;
  int g4 = lane >> 4;                         // 0..3 (k-slot group)
  int lrow = lane >> 3;                       // 0..7 staging row within 8-row span
  int lswz = ((lane & 7) ^ lrow) * 8;         // pre-swizzled source octet (elements)

  f32x4 acc[4][4];
#pragma unroll
  for (int mi = 0; mi < 4; mi++)
#pragma unroll
    for (int ni = 0; ni < 4; ni++) acc[mi][ni] = (f32x4){0.f, 0.f, 0.f, 0.f};

  for (int k0 = 0; k0 < K; k0 += 64) {
#pragma unroll
    for (int i = 0; i < 4; i++) {
      int r = wave * 32 + i * 8;  // wave-uniform row base
      gload_lds16(Ab + (size_t)(m0 + r + lrow) * lda + k0 + lswz, &As[r * 64]);
      gload_lds16(Bb + (size_t)(n0 + r + lrow) * ldb + k0 + lswz, &Bs[r * 64]);
    }
    __syncthreads();
#pragma unroll
    for (int kk = 0; kk < 2; kk++) {
      bf16x8 af[4], bfr[4];
#pragma unroll
      for (int mi = 0; mi < 4; mi++) {
        int arow = wm + mi * 16 + lr;
        int aoct = (kk * 4 + g4) ^ (lr & 7);
        af[mi] = *(const bf16x8*)&As[arow * 64 + aoct * 8];
      }
#pragma unroll
      for (int ni = 0; ni < 4; ni++) {
        int brow = wn + ni * 16 + lr;
        int boct = (kk * 4 + g4) ^ (lr & 7);
        bfr[ni] = *(const bf16x8*)&Bs[brow * 64 + boct * 8];
      }
#pragma unroll
      for (int mi = 0; mi < 4; mi++)
#pragma unroll
        for (int ni = 0; ni < 4; ni++)
          acc[mi][ni] = __builtin_amdgcn_mfma_f32_16x16x32_bf16(af[mi], bfr[ni],
                                                                acc[mi][ni], 0, 0, 0);
    }
    __syncthreads();
  }
  int r0 = (lane >> 4) * 4;
#pragma unroll
  for (int mi = 0; mi < 4; mi++)
#pragma unroll
    for (int ni = 0; ni < 4; ni++)
#pragma unroll
      for (int r = 0; r < 4; r++) {
        int row = m0 + wm + mi * 16 + r0 + r;
        int col = n0 + wn + ni * 16 + (lane & 15);
        size_t idx = (size_t)bz * cStride + (size_t)row * ldc + col;
        if (BF16OUT)
          ((u16*)Cout)[idx] = f2bf(acc[mi][ni][r]);
        else
          ((float*)Cout)[idx] = acc[mi][ni][r];
      }
}

// ---------------- K2: depthwise 3x3 on planar layout (q,k channels only) ----------
// grid (8 ystrips, 768 ch, 4 b). Block: one channel, 16 rows x 128 cols.
// LDS: 18 rows x (8 pad | 128 data | 8 pad) bf16, zero pads -> no branches.
__global__ __launch_bounds__(256) void dwconv_planar_kernel(const u16* __restrict__ qkvP,
                                                            const float* __restrict__ w_dw,
                                                            u16* __restrict__ qkvCP,
                                                            float* __restrict__ nrmp) {
  __shared__ u16 lrows[18 * 144];
  __shared__ float red[4];
  int strip = blockIdx.x, ch = blockIdx.y, b = blockIdx.z;
  int ys = strip * 16;
  int t = threadIdx.x;
  const u16* plane = qkvP + (size_t)ch * NTOT + b * HWN;
  u16* oplane = qkvCP + (size_t)ch * NTOT + b * HWN;

#pragma unroll
  for (int it = 0; it < 2; it++) {
    int ul = t + it * 256;
    if (ul < 324) {
      int row = ul / 18, u = ul % 18;    // row 0..17, unit 0..17 (16B units)
      int gy = ys - 1 + row;
      bf16x8 v = {0, 0, 0, 0, 0, 0, 0, 0};
      if (u >= 1 && u <= 16 && gy >= 0 && gy < 128)
        v = *(const bf16x8*)&plane[gy * IMG + (u - 1) * 8];
      *(bf16x8*)((char*)lrows + row * 288 + u * 16) = v;
    }
  }
  float wt[9];
#pragma unroll
  for (int r = 0; r < 9; r++) wt[r] = w_dw[ch * 9 + r];
  __syncthreads();

  int xo = t & 15, yl = t >> 4;          // 16 x-octets, 16 rows
  float win[3][10];
#pragma unroll
  for (int d = 0; d < 3; d++) {
    const char* base = (const char*)lrows + (yl + d) * 288 + xo * 16;
    bf16x8 rA = *(const bf16x8*)(base);
    bf16x8 rB = *(const bf16x8*)(base + 16);
    bf16x8 rC = *(const bf16x8*)(base + 32);
    win[d][0] = bf2f((u16)rA[7]);
#pragma unroll
    for (int k2 = 0; k2 < 8; k2++) win[d][k2 + 1] = bf2f((u16)rB[k2]);
    win[d][9] = bf2f((u16)rC[0]);
  }
  float accv[8] = {0.f, 0.f, 0.f, 0.f, 0.f, 0.f, 0.f, 0.f};
#pragma unroll
  for (int d = 0; d < 3; d++)
#pragma unroll
    for (int dx = 0; dx < 3; dx++) {
      float w = wt[d * 3 + dx];
#pragma unroll
      for (int jj = 0; jj < 8; jj++) accv[jj] += win[d][jj + dx] * w;
    }
  bf16x8 o;
  float n2 = 0.f;
#pragma unroll
  for (int jj = 0; jj < 8; jj++) {
    o[jj] = (short)f2bf(accv[jj]);
    n2 += accv[jj] * accv[jj];
  }
  *(bf16x8*)&oplane[(ys + yl) * IMG + xo * 8] = o;

  // block-reduce norm^2
#pragma unroll
  for (int off2 = 32; off2 >= 1; off2 >>= 1) n2 += __shfl_xor(n2, off2);
  if ((t & 63) == 0) red[t >> 6] = n2;
  __syncthreads();
  if (t == 0)
    nrmp[((size_t)b * 8 + strip) * 768 + ch] = red[0] + red[1] + red[2] + red[3];
}

// ---------------- K2v: fused depthwise 3x3 (v) + transpose -> vT [b*n][384] --------
// grid (128 y, 6 cg, 4 b). Block: 64 v-channels x 1 row x 128 px.
// LDS in: [3 rows][64 ch][8 zpad | 128 data | 8 zpad] stride VSTR; out [128 px][72].
__global__ __launch_bounds__(256) void dwconv_vtrans_kernel(const u16* __restrict__ qkvP,
                                                            const float* __restrict__ w_dw,
                                                            u16* __restrict__ vT) {
  __shared__ u16 in3[3 * 64 * VSTR];
  __shared__ u16 ot[128 * 72];
  int y = blockIdx.x, cg = blockIdx.y, b = blockIdx.z;
  int t = threadIdx.x;
  int ch0 = 768 + cg * 64;

  // zero apron octets: 3 rows x 64 ch x 2 sides = 384 items, 256 threads -> 2 iters
#pragma unroll
  for (int it = 0; it < 2; it++) {
    int ul = t + it * 256;
    if (ul < 384) {
      int d = ul >> 7, r = ul & 127;   // d 0..2, r 0..127
      int ch = r >> 1, side = r & 1;
      *(bf16x8*)&in3[(d * 64 + ch) * VSTR + side * 136] = (bf16x8){0, 0, 0, 0, 0, 0, 0, 0};
    }
  }
  // stage 3 rows x 64 ch x 16 data octets (px p at elem idx 8+p)
#pragma unroll
  for (int i = 0; i < 12; i++) {
    int u = t + i * 256;               // 0..3071
    int d = u >> 10, ch = (u >> 4) & 63, o = u & 15;
    int yn = y - 1 + d;
    bf16x8 v = {0, 0, 0, 0, 0, 0, 0, 0};
    if (yn >= 0 && yn < 128)
      v = *(const bf16x8*)&qkvP[(size_t)(ch0 + ch) * NTOT + b * HWN + yn * IMG + o * 8];
    *(bf16x8*)&in3[(d * 64 + ch) * VSTR + 8 + o * 8] = v;
  }
  int c = t & 63;
  float wt[9];
#pragma unroll
  for (int r = 0; r < 9; r++) wt[r] = w_dw[(ch0 + c) * 9 + r];
  __syncthreads();

#pragma unroll
  for (int i = 0; i < 4; i++) {
    int oct = (t >> 6) + i * 4;        // 0..15
    float win[3][10];
#pragma unroll
    for (int d = 0; d < 3; d++) {
      const u16* base = &in3[(d * 64 + c) * VSTR + oct * 8];
      bf16x8 rA = *(const bf16x8*)(base);        // px oct*8-8 .. -1  (need [7])
      bf16x8 rB = *(const bf16x8*)(base + 8);    // px oct*8 .. +7
      bf16x8 rC = *(const bf16x8*)(base + 16);   // px oct*8+8 ..     (need [0])
      win[d][0] = bf2f((u16)rA[7]);
#pragma unroll
      for (int k2 = 0; k2 < 8; k2++) win[d][k2 + 1] = bf2f((u16)rB[k2]);
      win[d][9] = bf2f((u16)rC[0]);
    }
    float accv[8] = {0.f, 0.f, 0.f, 0.f, 0.f, 0.f, 0.f, 0.f};
#pragma unroll
    for (int d = 0; d < 3; d++)
#pragma unroll
      for (int dx = 0; dx < 3; dx++) {
        float w = wt[d * 3 + dx];
#pragma unroll
        for (int jj = 0; jj < 8; jj++) accv[jj] += win[d][jj + dx] * w;
      }
#pragma unroll
    for (int jj = 0; jj < 8; jj++) ot[(oct * 8 + jj) * 72 + c] = f2bf(accv[jj]);
  }
  __syncthreads();

  // coalesced pixel-major write: vT[(b*HWN + y*128 + px)*384 + cg*64 + co*8]
#pragma unroll
  for (int i = 0; i < 4; i++) {
    int u = t + i * 256;               // 0..1023
    int px = u >> 3, co = u & 7;
    bf16x8 v = *(const bf16x8*)&ot[px * 72 + co * 8];
    *(bf16x8*)&vT[((size_t)b * HWN + y * IMG + px) * DIMC + cg * 64 + co * 8] = v;
  }
}

// ---------------- K3: Gram S = q . k^T per (b,h) from planar q,k ----------------
// grid (KC, 8 h, 4 b). K-chunk 1024, tiles of 128; 272B row stride.
__global__ __launch_bounds__(256) void gram_kernel(const u16* __restrict__ qkvCP,
                                                   float* __restrict__ partials) {
  __shared__ u16 qs[48 * 136];
  __shared__ u16 ks2[48 * 136];
  __shared__ float Sred[4 * 2304];
  int kc = blockIdx.x, h = blockIdx.y, b = blockIdx.z;
  int t = threadIdx.x, wave = t >> 6, lane = t & 63;
  int lr = lane & 15, lk = (lane >> 4) * 8;
  int nbase = b * HWN + kc * (HWN / KC);

  f32x4 acc[3][3];
#pragma unroll
  for (int mi = 0; mi < 3; mi++)
#pragma unroll
    for (int ni = 0; ni < 3; ni++) acc[mi][ni] = (f32x4){0.f, 0.f, 0.f, 0.f};

  for (int tile = 0; tile < (HWN / KC) / 128; tile++) {
    int n0 = nbase + tile * 128;
    __syncthreads();
    // stage q[48][128] and k[48][128]: 2 * 48 rows * 16 octets = 1536 octet-loads
#pragma unroll
    for (int i = 0; i < 6; i++) {
      int u = t + i * 256;               // 0..1535
      int m = (u >= 768) ? 1 : 0;
      int uu = u - m * 768;              // 0..767
      int r = uu >> 4, cu = uu & 15;     // row 0..47, octet 0..15 (128 pixels)
      int chh = m ? 384 + h * CHD + r : h * CHD + r;
      bf16x8 v = *(const bf16x8*)&qkvCP[(size_t)chh * NTOT + n0 + cu * 8];
      *(bf16x8*)((char*)(m ? ks2 : qs) + r * 272 + cu * 16) = v;
    }
    __syncthreads();
    bf16x8 af[3], bfr[3];
#pragma unroll
    for (int mi = 0; mi < 3; mi++)
      af[mi] = *(const bf16x8*)((char*)qs + (mi * 16 + lr) * 272 + wave * 64 + lk * 2);
#pragma unroll
    for (int ni = 0; ni < 3; ni++)
      bfr[ni] = *(const bf16x8*)((char*)ks2 + (ni * 16 + lr) * 272 + wave * 64 + lk * 2);
#pragma unroll
    for (int mi = 0; mi < 3; mi++)
#pragma unroll
      for (int ni = 0; ni < 3; ni++)
        acc[mi][ni] = __builtin_amdgcn_mfma_f32_16x16x32_bf16(af[mi], bfr[ni],
                                                              acc[mi][ni], 0, 0, 0);
  }

#pragma unroll
  for (int mi = 0; mi < 3; mi++)
#pragma unroll
    for (int ni = 0; ni < 3; ni++)
#pragma unroll
      for (int r = 0; r < 4; r++) {
        int crow = mi * 16 + (lane >> 4) * 4 + r;
        int dcol = ni * 16 + (lane & 15);
        Sred[wave * 2304 + crow * 48 + dcol] = acc[mi][ni][r];
      }
  __syncthreads();
  float* pout = partials + ((size_t)((b * NHEAD + h) * KC + kc)) * 2304;
  for (int idx = t; idx < 2304; idx += 256) {
    float s = 0.f;
#pragma unroll
    for (int w = 0; w < 4; w++) s += Sred[w * 2304 + idx];
    pout[idx] = s;
  }
}

// ---------------- K4: reduce partials+norms, normalize, softmax -> attn ----------------
__global__ __launch_bounds__(256) void softmax_kernel(const float* __restrict__ partials,
                                                      const float* __restrict__ nrmp,
                                                      const float* __restrict__ temp,
                                                      float* __restrict__ attn) {
  __shared__ float S[2304];
  __shared__ float nq[48], nk[48];
  int h = blockIdx.x, b = blockIdx.y;
  const float* p = partials + (size_t)(b * NHEAD + h) * KC * 2304;
  for (int idx = threadIdx.x; idx < 2304; idx += 256) {
    float s = 0.f;
#pragma unroll
    for (int kc = 0; kc < KC; kc++) s += p[kc * 2304 + idx];
    S[idx] = s;
  }
  if (threadIdx.x < 96) {
    int tq = threadIdx.x;
    int c = (tq < 48) ? tq : tq - 48;
    int ch = (tq < 48) ? h * CHD + c : DIMC + h * CHD + c;
    float s = 0.f;
#pragma unroll
    for (int st = 0; st < 8; st++) s += nrmp[((size_t)b * 8 + st) * 768 + ch];
    float nv = fmaxf(sqrtf(s), 1e-12f);
    if (tq < 48) nq[c] = nv; else nk[c] = nv;
  }
  __syncthreads();
  float tf = temp[h];
  float* A = attn + (size_t)(b * NHEAD + h) * 2304;
  if (threadIdx.x < CHD) {
    int c = threadIdx.x;
    float inq = 1.f / nq[c];
    float mx = -1e30f;
    float row[48];
    for (int d = 0; d < CHD; d++) {
      float v = S[c * 48 + d] * tf * inq / nk[d];
      row[d] = v;
      mx = fmaxf(mx, v);
    }
    float sum = 0.f;
    for (int d = 0; d < CHD; d++) {
      float e = expf(row[d] - mx);
      row[d] = e;
      sum += e;
    }
    float inv = 1.f / sum;
    for (int d = 0; d < CHD; d++) A[c * 48 + d] = row[d] * inv;
  }
}

// ---------------- K5: Mf[b,o,h*48+d] = sum_c w_proj[o,h*48+c]*attn[b,h,c,d] ----------
__global__ __launch_bounds__(256) void build_mf_kernel(const float* __restrict__ attn,
                                                       const float* __restrict__ w_proj,
                                                       u16* __restrict__ Mf) {
  __shared__ float al[NHEAD * 2304];
  int b = blockIdx.y, o0 = blockIdx.x * 32;
  for (int i = threadIdx.x; i < NHEAD * 2304; i += 256)
    al[i] = attn[(size_t)b * NHEAD * 2304 + i];
  __syncthreads();
  for (int idx = threadIdx.x; idx < 32 * DIMC; idx += 256) {
    int ol = idx / DIMC, cp = idx % DIMC;
    int o = o0 + ol, h = cp / CHD, d = cp % CHD;
    float s = 0.f;
#pragma unroll
    for (int c = 0; c < CHD; c++)
      s += w_proj[(size_t)o * DIMC + h * CHD + c] * al[h * 2304 + c * 48 + d];
    Mf[((size_t)b * DIMC + o) * DIMC + cp] = f2bf(s);
  }
}

// ---------------- launch ----------------
extern "C" void kernel_launch(void* const* d_in, const int* in_sizes, int n_in,
                              void* d_out, int out_size, void* d_ws, size_t ws_size,
                              hipStream_t stream) {
  const float* x      = (const float*)d_in[0];
  const float* w_qkv  = (const float*)d_in[1];
  const float* w_dw   = (const float*)d_in[2];
  const float* w_proj = (const float*)d_in[3];
  const float* temp   = (const float*)d_in[4];
  float* out = (float*)d_out;

  char* ws = (char*)d_ws;
  size_t off = 0;
  u16* xT = (u16*)(ws + off);                // [b*n][384] bf16 (dead after gemm1)
  size_t xT_off = off;
  off += (size_t)NTOT * DIMC * 2;            //  50,331,648
  u16* qkvP = (u16*)(ws + off);              // [1152][b*n] planar (pre-conv)
  off += (size_t)CDIM * NTOT * 2;            // 150,994,944
  u16* qkvCP = (u16*)(ws + off);             // [768][b*n] planar conv'd q,k only
  off += (size_t)768 * NTOT * 2;             // 100,663,296
  u16* wq16 = (u16*)(ws + off);
  off += (size_t)CDIM * DIMC * 2;            //     884,736
  float* nrmp = (float*)(ws + off);          // [b][8 strips][768]
  off += (size_t)NBATCH * 8 * 768 * 4;       //      98,304
  float* partials = (float*)(ws + off);      // [b][h][KC][2304]
  off += (size_t)NBATCH * NHEAD * KC * 2304 * 4;  // 4,718,592
  float* attn = (float*)(ws + off);
  off += (size_t)NBATCH * NHEAD * 2304 * 4;  //     294,912
  u16* Mf = (u16*)(ws + off);
  off += (size_t)NBATCH * DIMC * DIMC * 2;   //   1,179,648
  u16* vT = (u16*)(ws + xT_off);             // [b*n][384] bf16, aliases dead xT

  if (ws_size < off) return;  // fail loudly (zero output) if workspace too small

  convert_wq_kernel<<<dim3((CDIM * DIMC + 255) / 256), dim3(256), 0, stream>>>(
      w_qkv, wq16, CDIM * DIMC);
  transpose_x_kernel<<<dim3(HWN / 32, DIMC / 32, NBATCH), dim3(256), 0, stream>>>(x, xT);
  // gemm1 (planar out): qkvP[o][n] = wq16[o,:] . xT[n,:];  M=1152, N=65536, K=384
  // split into two N=32768 halves (diagnostic: surfaces second-tier kernels in top-5)
  // each: grid = 8 * MBLK(9) * (256/8) = 2304, XCD-swizzled
  gemm_bt_kernel<1><<<dim3(2304, 1, 1), dim3(256), 0, stream>>>(
      wq16, xT, (void*)qkvP, 9, DIMC, DIMC, DIMC, NTOT, 0ULL, 0ULL, 0ULL);
  gemm_bt_kernel<1><<<dim3(2304, 1, 1), dim3(256), 0, stream>>>(
      wq16, xT + (size_t)32768 * DIMC, (void*)(qkvP + 32768), 9,
      DIMC, DIMC, DIMC, NTOT, 0ULL, 0ULL, 0ULL);
  // q,k conv (planar out) + norms
  dwconv_planar_kernel<<<dim3(8, 768, NBATCH), dim3(256), 0, stream>>>(
      qkvP, w_dw, qkvCP, nrmp);
  // v conv fused with transpose -> vT pixel-major (overwrites dead xT)
  dwconv_vtrans_kernel<<<dim3(IMG, 6, NBATCH), dim3(256), 0, stream>>>(qkvP, w_dw, vT);
  gram_kernel<<<dim3(KC, NHEAD, NBATCH), dim3(256), 0, stream>>>(qkvCP, partials);
  softmax_kernel<<<dim3(NHEAD, NBATCH), dim3(256), 0, stream>>>(partials, nrmp, temp, attn);
  build_mf_kernel<<<dim3(DIMC / 32, NBATCH), dim3(256), 0, stream>>>(attn, w_proj, Mf);
  // gemm2: out[b,o,n] = Mf[b,o,:] . vT[b,n,:];  M=384, N=16384 per batch
  // grid = 8 * MBLK(3) * (128/8) = 384 per batch, XCD-swizzled
  gemm_bt_kernel<0><<<dim3(384, 1, NBATCH), dim3(256), 0, stream>>>(
      Mf, vT, (void*)out, 3, DIMC, DIMC, DIMC, HWN,
      (unsigned long long)DIMC * DIMC, (unsigned long long)HWN * DIMC,
      (unsigned long long)DIMC * HWN);
}

// Round 13
// 340.785 us; speedup vs baseline: 1.0610x; 1.0610x over previous
//
#include <hip/hip_runtime.h>
#include <math.h>

typedef unsigned short u16;
typedef unsigned int u32;
typedef __attribute__((ext_vector_type(8))) short bf16x8;
typedef __attribute__((ext_vector_type(4))) float f32x4;

#define IMG 128
#define HWN 16384
#define NTOT 65536          // 4 * 16384 pixels
#define DIMC 384
#define CDIM 1152
#define NBATCH 4
#define NHEAD 8
#define CHD 48
#define KC 16
#define VSTR 152            // in3 row stride (elems): 19 x 16B units -> 4-way max on reads

__device__ __forceinline__ u16 f2bf(float f) {
  union { float f; u32 u; } x; x.f = f;
  u32 r = x.u + 0x7fffu + ((x.u >> 16) & 1u);
  return (u16)(r >> 16);
}
__device__ __forceinline__ float bf2f(u16 v) {
  union { u32 u; float f; } x; x.u = ((u32)v) << 16;
  return x.f;
}
__device__ __forceinline__ void gload_lds16(const u16* g, u16* lds) {
  __builtin_amdgcn_global_load_lds((const __attribute__((address_space(1))) void*)g,
                                   (__attribute__((address_space(3))) void*)lds, 16, 0, 0);
}

// ---------------- tiny: convert w_qkv to bf16 ----------------
__global__ void convert_wq_kernel(const float* __restrict__ in, u16* __restrict__ out, int n) {
  int i = blockIdx.x * 256 + threadIdx.x;
  if (i < n) out[i] = f2bf(in[i]);
}

// ---------------- K0: x [b,c,n] f32 -> xT [b*n, c] bf16 ----------------
__global__ __launch_bounds__(256) void transpose_x_kernel(const float* __restrict__ x,
                                                          u16* __restrict__ xT) {
  __shared__ float tile[32][33];
  int n0 = blockIdx.x * 32, c0 = blockIdx.y * 32, b = blockIdx.z;
  const float* xb = x + (size_t)b * DIMC * HWN;
  u16* xTb = xT + (size_t)b * HWN * DIMC;
  int tx = threadIdx.x & 31, ty = threadIdx.x >> 5;
#pragma unroll
  for (int i = 0; i < 32; i += 8)
    tile[ty + i][tx] = xb[(size_t)(c0 + ty + i) * HWN + n0 + tx];
  __syncthreads();
  int cp = threadIdx.x & 15, nl = threadIdx.x >> 4;   // 16 c-pairs, 16 n-rows
#pragma unroll
  for (int i = 0; i < 2; i++) {
    int n = nl + i * 16;
    u32 o = (u32)f2bf(tile[cp * 2][n]) | ((u32)f2bf(tile[cp * 2 + 1][n]) << 16);
    *(u32*)&xTb[(size_t)(n0 + n) * DIMC + c0 + cp * 2] = o;
  }
}

// ---------------- GEMM (m97 structure + T2 swizzle): C = A[M,:K] * B[N,:K]^T ------
// Linear LDS dest; SOURCE octet pre-swizzled with (l&7)^(l>>3); fragment read XORs
// octet with row&7.  LDS(R,o) = global(R, o^(R&7)).
// 1-D grid.x = 8 * MBLK * (NBLK/8); XCD-aware decode (same n-tile -> same XCD).
template <int BF16OUT>
__global__ __launch_bounds__(256) void gemm_bt_kernel(
    const u16* __restrict__ A, const u16* __restrict__ B, void* __restrict__ Cout,
    int MBLK, int K, int lda, int ldb, int ldc,
    unsigned long long aStride, unsigned long long bStride, unsigned long long cStride) {
  __shared__ u16 As[128 * 64];
  __shared__ u16 Bs[128 * 64];
  int bz = blockIdx.z;
  const u16* Ab = A + (size_t)bz * aStride;
  const u16* Bb = B + (size_t)bz * bStride;
  int bid = blockIdx.x;
  int xcd = bid & 7, j = bid >> 3;
  int mb = j % MBLK, nb = (j / MBLK) * 8 + xcd;
  int n0 = nb * 128, m0 = mb * 128;
  int t = threadIdx.x;
  int wave = t >> 6, lane = t & 63;
  int wm = (wave >> 1) * 64, wn = (wave & 1) * 64;
  int lr = lane & 15;
  int g4 = lane >> 4;                         // 0..3 (k-slot group)
  int lrow = lane >> 3;                       // 0..7 staging row within 8-row span
  int lswz = ((lane & 7) ^ lrow) * 8;         // pre-swizzled source octet (elements)

  f32x4 acc[4][4];
#pragma unroll
  for (int mi = 0; mi < 4; mi++)
#pragma unroll
    for (int ni = 0; ni < 4; ni++) acc[mi][ni] = (f32x4){0.f, 0.f, 0.f, 0.f};

  for (int k0 = 0; k0 < K; k0 += 64) {
#pragma unroll
    for (int i = 0; i < 4; i++) {
      int r = wave * 32 + i * 8;  // wave-uniform row base
      gload_lds16(Ab + (size_t)(m0 + r + lrow) * lda + k0 + lswz, &As[r * 64]);
      gload_lds16(Bb + (size_t)(n0 + r + lrow) * ldb + k0 + lswz, &Bs[r * 64]);
    }
    __syncthreads();
#pragma unroll
    for (int kk = 0; kk < 2; kk++) {
      bf16x8 af[4], bfr[4];
#pragma unroll
      for (int mi = 0; mi < 4; mi++) {
        int arow = wm + mi * 16 + lr;
        int aoct = (kk * 4 + g4) ^ (lr & 7);
        af[mi] = *(const bf16x8*)&As[arow * 64 + aoct * 8];
      }
#pragma unroll
      for (int ni = 0; ni < 4; ni++) {
        int brow = wn + ni * 16 + lr;
        int boct = (kk * 4 + g4) ^ (lr & 7);
        bfr[ni] = *(const bf16x8*)&Bs[brow * 64 + boct * 8];
      }
#pragma unroll
      for (int mi = 0; mi < 4; mi++)
#pragma unroll
        for (int ni = 0; ni < 4; ni++)
          acc[mi][ni] = __builtin_amdgcn_mfma_f32_16x16x32_bf16(af[mi], bfr[ni],
                                                                acc[mi][ni], 0, 0, 0);
    }
    __syncthreads();
  }
  int r0 = (lane >> 4) * 4;
#pragma unroll
  for (int mi = 0; mi < 4; mi++)
#pragma unroll
    for (int ni = 0; ni < 4; ni++)
#pragma unroll
      for (int r = 0; r < 4; r++) {
        int row = m0 + wm + mi * 16 + r0 + r;
        int col = n0 + wn + ni * 16 + (lane & 15);
        size_t idx = (size_t)bz * cStride + (size_t)row * ldc + col;
        if (BF16OUT)
          ((u16*)Cout)[idx] = f2bf(acc[mi][ni][r]);
        else
          ((float*)Cout)[idx] = acc[mi][ni][r];
      }
}

// ---------------- K2: depthwise 3x3 on planar layout (q,k channels only) ----------
// grid (8 ystrips, 768 ch, 4 b). Block: one channel, 16 rows x 128 cols.
__global__ __launch_bounds__(256) void dwconv_planar_kernel(const u16* __restrict__ qkvP,
                                                            const float* __restrict__ w_dw,
                                                            u16* __restrict__ qkvCP,
                                                            float* __restrict__ nrmp) {
  __shared__ u16 lrows[18 * 144];
  __shared__ float red[4];
  int strip = blockIdx.x, ch = blockIdx.y, b = blockIdx.z;
  int ys = strip * 16;
  int t = threadIdx.x;
  const u16* plane = qkvP + (size_t)ch * NTOT + b * HWN;
  u16* oplane = qkvCP + (size_t)ch * NTOT + b * HWN;

#pragma unroll
  for (int it = 0; it < 2; it++) {
    int ul = t + it * 256;
    if (ul < 324) {
      int row = ul / 18, u = ul % 18;    // row 0..17, unit 0..17 (16B units)
      int gy = ys - 1 + row;
      bf16x8 v = {0, 0, 0, 0, 0, 0, 0, 0};
      if (u >= 1 && u <= 16 && gy >= 0 && gy < 128)
        v = *(const bf16x8*)&plane[gy * IMG + (u - 1) * 8];
      *(bf16x8*)((char*)lrows + row * 288 + u * 16) = v;
    }
  }
  float wt[9];
#pragma unroll
  for (int r = 0; r < 9; r++) wt[r] = w_dw[ch * 9 + r];
  __syncthreads();

  int xo = t & 15, yl = t >> 4;          // 16 x-octets, 16 rows
  float win[3][10];
#pragma unroll
  for (int d = 0; d < 3; d++) {
    const char* base = (const char*)lrows + (yl + d) * 288 + xo * 16;
    bf16x8 rA = *(const bf16x8*)(base);
    bf16x8 rB = *(const bf16x8*)(base + 16);
    bf16x8 rC = *(const bf16x8*)(base + 32);
    win[d][0] = bf2f((u16)rA[7]);
#pragma unroll
    for (int k2 = 0; k2 < 8; k2++) win[d][k2 + 1] = bf2f((u16)rB[k2]);
    win[d][9] = bf2f((u16)rC[0]);
  }
  float accv[8] = {0.f, 0.f, 0.f, 0.f, 0.f, 0.f, 0.f, 0.f};
#pragma unroll
  for (int d = 0; d < 3; d++)
#pragma unroll
    for (int dx = 0; dx < 3; dx++) {
      float w = wt[d * 3 + dx];
#pragma unroll
      for (int jj = 0; jj < 8; jj++) accv[jj] += win[d][jj + dx] * w;
    }
  bf16x8 o;
  float n2 = 0.f;
#pragma unroll
  for (int jj = 0; jj < 8; jj++) {
    o[jj] = (short)f2bf(accv[jj]);
    n2 += accv[jj] * accv[jj];
  }
  *(bf16x8*)&oplane[(ys + yl) * IMG + xo * 8] = o;

  // block-reduce norm^2
#pragma unroll
  for (int off2 = 32; off2 >= 1; off2 >>= 1) n2 += __shfl_xor(n2, off2);
  if ((t & 63) == 0) red[t >> 6] = n2;
  __syncthreads();
  if (t == 0)
    nrmp[((size_t)b * 8 + strip) * 768 + ch] = red[0] + red[1] + red[2] + red[3];
}

// ---------------- K2v: fused depthwise 3x3 (v) + transpose -> vT [b*n][384] --------
// grid (128 y, 12 cg, 4 b). Block: 32 v-channels x 1 row x 128 px.
// LDS: in3 [3][32][VSTR] = 29.2KB + ot [128][40] = 10.2KB -> 4 blocks/CU.
__global__ __launch_bounds__(256) void dwconv_vtrans_kernel(const u16* __restrict__ qkvP,
                                                            const float* __restrict__ w_dw,
                                                            u16* __restrict__ vT) {
  __shared__ u16 in3[3 * 32 * VSTR];
  __shared__ u16 ot[128 * 40];
  int y = blockIdx.x, cg = blockIdx.y, b = blockIdx.z;
  int t = threadIdx.x;
  int ch0 = 768 + cg * 32;

  // zero apron octets: 3 rows x 32 ch x 2 sides = 192 items (single pass)
  if (t < 192) {
    int d = t / 64, r = t & 63;        // d 0..2, r 0..63
    int ch = r >> 1, side = r & 1;
    *(bf16x8*)&in3[(d * 32 + ch) * VSTR + side * 136] = (bf16x8){0, 0, 0, 0, 0, 0, 0, 0};
  }
  // stage 3 rows x 32 ch x 16 data octets (px p at elem idx 8+p)
#pragma unroll
  for (int i = 0; i < 6; i++) {
    int u = t + i * 256;               // 0..1535
    int d = u >> 9, ch = (u >> 4) & 31, o = u & 15;
    int yn = y - 1 + d;
    bf16x8 v = {0, 0, 0, 0, 0, 0, 0, 0};
    if (yn >= 0 && yn < 128)
      v = *(const bf16x8*)&qkvP[(size_t)(ch0 + ch) * NTOT + b * HWN + yn * IMG + o * 8];
    *(bf16x8*)&in3[(d * 32 + ch) * VSTR + 8 + o * 8] = v;
  }
  int c = t & 31;
  float wt[9];
#pragma unroll
  for (int r = 0; r < 9; r++) wt[r] = w_dw[(ch0 + c) * 9 + r];
  __syncthreads();

#pragma unroll
  for (int i = 0; i < 2; i++) {
    int oct = (t >> 5) + i * 8;        // 0..15
    float win[3][10];
#pragma unroll
    for (int d = 0; d < 3; d++) {
      const u16* base = &in3[(d * 32 + c) * VSTR + oct * 8];
      bf16x8 rA = *(const bf16x8*)(base);        // need [7] (px oct*8-1)
      bf16x8 rB = *(const bf16x8*)(base + 8);    // px oct*8 .. +7
      bf16x8 rC = *(const bf16x8*)(base + 16);   // need [0] (px oct*8+8)
      win[d][0] = bf2f((u16)rA[7]);
#pragma unroll
      for (int k2 = 0; k2 < 8; k2++) win[d][k2 + 1] = bf2f((u16)rB[k2]);
      win[d][9] = bf2f((u16)rC[0]);
    }
    float accv[8] = {0.f, 0.f, 0.f, 0.f, 0.f, 0.f, 0.f, 0.f};
#pragma unroll
    for (int d = 0; d < 3; d++)
#pragma unroll
      for (int dx = 0; dx < 3; dx++) {
        float w = wt[d * 3 + dx];
#pragma unroll
        for (int jj = 0; jj < 8; jj++) accv[jj] += win[d][jj + dx] * w;
      }
#pragma unroll
    for (int jj = 0; jj < 8; jj++) ot[(oct * 8 + jj) * 40 + c] = f2bf(accv[jj]);
  }
  __syncthreads();

  // coalesced pixel-major write: 128 px x 4 octets (32 ch)
#pragma unroll
  for (int i = 0; i < 2; i++) {
    int u = t + i * 256;               // 0..511
    int px = u >> 2, co = u & 3;
    bf16x8 v = *(const bf16x8*)&ot[px * 40 + co * 8];
    *(bf16x8*)&vT[((size_t)b * HWN + y * IMG + px) * DIMC + cg * 32 + co * 8] = v;
  }
}

// ---------------- K3: Gram S = q . k^T per (b,h) from planar q,k ----------------
// grid (KC, 8 h, 4 b). K-chunk 1024, tiles of 128; 272B row stride.
__global__ __launch_bounds__(256) void gram_kernel(const u16* __restrict__ qkvCP,
                                                   float* __restrict__ partials) {
  __shared__ u16 qs[48 * 136];
  __shared__ u16 ks2[48 * 136];
  __shared__ float Sred[4 * 2304];
  int kc = blockIdx.x, h = blockIdx.y, b = blockIdx.z;
  int t = threadIdx.x, wave = t >> 6, lane = t & 63;
  int lr = lane & 15, lk = (lane >> 4) * 8;
  int nbase = b * HWN + kc * (HWN / KC);

  f32x4 acc[3][3];
#pragma unroll
  for (int mi = 0; mi < 3; mi++)
#pragma unroll
    for (int ni = 0; ni < 3; ni++) acc[mi][ni] = (f32x4){0.f, 0.f, 0.f, 0.f};

  for (int tile = 0; tile < (HWN / KC) / 128; tile++) {
    int n0 = nbase + tile * 128;
    __syncthreads();
    // stage q[48][128] and k[48][128]: 1536 octet-loads
#pragma unroll
    for (int i = 0; i < 6; i++) {
      int u = t + i * 256;               // 0..1535
      int m = (u >= 768) ? 1 : 0;
      int uu = u - m * 768;              // 0..767
      int r = uu >> 4, cu = uu & 15;     // row 0..47, octet 0..15
      int chh = m ? 384 + h * CHD + r : h * CHD + r;
      bf16x8 v = *(const bf16x8*)&qkvCP[(size_t)chh * NTOT + n0 + cu * 8];
      *(bf16x8*)((char*)(m ? ks2 : qs) + r * 272 + cu * 16) = v;
    }
    __syncthreads();
    bf16x8 af[3], bfr[3];
#pragma unroll
    for (int mi = 0; mi < 3; mi++)
      af[mi] = *(const bf16x8*)((char*)qs + (mi * 16 + lr) * 272 + wave * 64 + lk * 2);
#pragma unroll
    for (int ni = 0; ni < 3; ni++)
      bfr[ni] = *(const bf16x8*)((char*)ks2 + (ni * 16 + lr) * 272 + wave * 64 + lk * 2);
#pragma unroll
    for (int mi = 0; mi < 3; mi++)
#pragma unroll
      for (int ni = 0; ni < 3; ni++)
        acc[mi][ni] = __builtin_amdgcn_mfma_f32_16x16x32_bf16(af[mi], bfr[ni],
                                                              acc[mi][ni], 0, 0, 0);
  }

#pragma unroll
  for (int mi = 0; mi < 3; mi++)
#pragma unroll
    for (int ni = 0; ni < 3; ni++)
#pragma unroll
      for (int r = 0; r < 4; r++) {
        int crow = mi * 16 + (lane >> 4) * 4 + r;
        int dcol = ni * 16 + (lane & 15);
        Sred[wave * 2304 + crow * 48 + dcol] = acc[mi][ni][r];
      }
  __syncthreads();
  float* pout = partials + ((size_t)((b * NHEAD + h) * KC + kc)) * 2304;
  for (int idx = t; idx < 2304; idx += 256) {
    float s = 0.f;
#pragma unroll
    for (int w = 0; w < 4; w++) s += Sred[w * 2304 + idx];
    pout[idx] = s;
  }
}

// ---------------- K4: reduce partials+norms, normalize, softmax -> attn ----------------
__global__ __launch_bounds__(256) void softmax_kernel(const float* __restrict__ partials,
                                                      const float* __restrict__ nrmp,
                                                      const float* __restrict__ temp,
                                                      float* __restrict__ attn) {
  __shared__ float S[2304];
  __shared__ float nq[48], nk[48];
  int h = blockIdx.x, b = blockIdx.y;
  const float* p = partials + (size_t)(b * NHEAD + h) * KC * 2304;
  for (int idx = threadIdx.x; idx < 2304; idx += 256) {
    float s = 0.f;
#pragma unroll
    for (int kc = 0; kc < KC; kc++) s += p[kc * 2304 + idx];
    S[idx] = s;
  }
  if (threadIdx.x < 96) {
    int tq = threadIdx.x;
    int c = (tq < 48) ? tq : tq - 48;
    int ch = (tq < 48) ? h * CHD + c : DIMC + h * CHD + c;
    float s = 0.f;
#pragma unroll
    for (int st = 0; st < 8; st++) s += nrmp[((size_t)b * 8 + st) * 768 + ch];
    float nv = fmaxf(sqrtf(s), 1e-12f);
    if (tq < 48) nq[c] = nv; else nk[c] = nv;
  }
  __syncthreads();
  float tf = temp[h];
  float* A = attn + (size_t)(b * NHEAD + h) * 2304;
  if (threadIdx.x < CHD) {
    int c = threadIdx.x;
    float inq = 1.f / nq[c];
    float mx = -1e30f;
    float row[48];
    for (int d = 0; d < CHD; d++) {
      float v = S[c * 48 + d] * tf * inq / nk[d];
      row[d] = v;
      mx = fmaxf(mx, v);
    }
    float sum = 0.f;
    for (int d = 0; d < CHD; d++) {
      float e = expf(row[d] - mx);
      row[d] = e;
      sum += e;
    }
    float inv = 1.f / sum;
    for (int d = 0; d < CHD; d++) A[c * 48 + d] = row[d] * inv;
  }
}

// ---------------- K5: Mf[b,o,h*48+d] = sum_c w_proj[o,h*48+c]*attn[b,h,c,d] ----------
__global__ __launch_bounds__(256) void build_mf_kernel(const float* __restrict__ attn,
                                                       const float* __restrict__ w_proj,
                                                       u16* __restrict__ Mf) {
  __shared__ float al[NHEAD * 2304];
  int b = blockIdx.y, o0 = blockIdx.x * 32;
  for (int i = threadIdx.x; i < NHEAD * 2304; i += 256)
    al[i] = attn[(size_t)b * NHEAD * 2304 + i];
  __syncthreads();
  for (int idx = threadIdx.x; idx < 32 * DIMC; idx += 256) {
    int ol = idx / DIMC, cp = idx % DIMC;
    int o = o0 + ol, h = cp / CHD, d = cp % CHD;
    float s = 0.f;
#pragma unroll
    for (int c = 0; c < CHD; c++)
      s += w_proj[(size_t)o * DIMC + h * CHD + c] * al[h * 2304 + c * 48 + d];
    Mf[((size_t)b * DIMC + o) * DIMC + cp] = f2bf(s);
  }
}

// ---------------- launch ----------------
extern "C" void kernel_launch(void* const* d_in, const int* in_sizes, int n_in,
                              void* d_out, int out_size, void* d_ws, size_t ws_size,
                              hipStream_t stream) {
  const float* x      = (const float*)d_in[0];
  const float* w_qkv  = (const float*)d_in[1];
  const float* w_dw   = (const float*)d_in[2];
  const float* w_proj = (const float*)d_in[3];
  const float* temp   = (const float*)d_in[4];
  float* out = (float*)d_out;

  char* ws = (char*)d_ws;
  size_t off = 0;
  u16* xT = (u16*)(ws + off);                // [b*n][384] bf16 (dead after gemm1)
  size_t xT_off = off;
  off += (size_t)NTOT * DIMC * 2;            //  50,331,648
  u16* qkvP = (u16*)(ws + off);              // [1152][b*n] planar (pre-conv)
  off += (size_t)CDIM * NTOT * 2;            // 150,994,944
  u16* qkvCP = (u16*)(ws + off);             // [768][b*n] planar conv'd q,k only
  off += (size_t)768 * NTOT * 2;             // 100,663,296
  u16* wq16 = (u16*)(ws + off);
  off += (size_t)CDIM * DIMC * 2;            //     884,736
  float* nrmp = (float*)(ws + off);          // [b][8 strips][768]
  off += (size_t)NBATCH * 8 * 768 * 4;       //      98,304
  float* partials = (float*)(ws + off);      // [b][h][KC][2304]
  off += (size_t)NBATCH * NHEAD * KC * 2304 * 4;  // 4,718,592
  float* attn = (float*)(ws + off);
  off += (size_t)NBATCH * NHEAD * 2304 * 4;  //     294,912
  u16* Mf = (u16*)(ws + off);
  off += (size_t)NBATCH * DIMC * DIMC * 2;   //   1,179,648
  u16* vT = (u16*)(ws + xT_off);             // [b*n][384] bf16, aliases dead xT

  if (ws_size < off) return;  // fail loudly (zero output) if workspace too small

  convert_wq_kernel<<<dim3((CDIM * DIMC + 255) / 256), dim3(256), 0, stream>>>(
      w_qkv, wq16, CDIM * DIMC);
  transpose_x_kernel<<<dim3(HWN / 32, DIMC / 32, NBATCH), dim3(256), 0, stream>>>(x, xT);
  // gemm1 (planar out): qkvP[o][n] = wq16[o,:] . xT[n,:];  M=1152, N=65536, K=384
  // grid = 8 * MBLK(9) * (512/8) = 4608, XCD-swizzled
  gemm_bt_kernel<1><<<dim3(4608, 1, 1), dim3(256), 0, stream>>>(
      wq16, xT, (void*)qkvP, 9, DIMC, DIMC, DIMC, NTOT, 0ULL, 0ULL, 0ULL);
  // q,k conv (planar out) + norms
  dwconv_planar_kernel<<<dim3(8, 768, NBATCH), dim3(256), 0, stream>>>(
      qkvP, w_dw, qkvCP, nrmp);
  // v conv fused with transpose -> vT pixel-major (overwrites dead xT)
  dwconv_vtrans_kernel<<<dim3(IMG, 12, NBATCH), dim3(256), 0, stream>>>(qkvP, w_dw, vT);
  gram_kernel<<<dim3(KC, NHEAD, NBATCH), dim3(256), 0, stream>>>(qkvCP, partials);
  softmax_kernel<<<dim3(NHEAD, NBATCH), dim3(256), 0, stream>>>(partials, nrmp, temp, attn);
  build_mf_kernel<<<dim3(DIMC / 32, NBATCH), dim3(256), 0, stream>>>(attn, w_proj, Mf);
  // gemm2: out[b,o,n] = Mf[b,o,:] . vT[b,n,:];  M=384, N=16384 per batch
  // grid = 8 * MBLK(3) * (128/8) = 384 per batch, XCD-swizzled
  gemm_bt_kernel<0><<<dim3(384, 1, NBATCH), dim3(256), 0, stream>>>(
      Mf, vT, (void*)out, 3, DIMC, DIMC, DIMC, HWN,
      (unsigned long long)DIMC * DIMC, (unsigned long long)HWN * DIMC,
      (unsigned long long)DIMC * HWN);
}